// Round 1
// baseline (4034.813 us; speedup 1.0000x reference)
//
#include <hip/hip_runtime.h>
#include <math.h>

#define NPG 1000
#define KTOP 500
#define C 64

// ---------------- degree count (in-degree over dst) ----------------
__global__ void deg_count_k(const int* __restrict__ ei, int* __restrict__ deg, int E) {
    int e = blockIdx.x * 256 + threadIdx.x;
    if (e < E) atomicAdd(&deg[ei[E + e]], 1);
}

// dinv = 1/sqrt(deg+1)   (+1 = self loop; deg >= 1 always)
__global__ void dinv_k(const int* __restrict__ deg, float* __restrict__ dinv, int N) {
    int i = blockIdx.x * 256 + threadIdx.x;
    if (i < N) dinv[i] = 1.0f / sqrtf((float)(deg[i] + 1));
}

// ---------------- h = x @ W  (N x 64 @ 64 x 64) ----------------
// block = 256 threads handles 64 consecutive rows; W staged in LDS.
__global__ void gemm_k(const float* __restrict__ x, const float* __restrict__ W,
                       float* __restrict__ h, int N) {
    __shared__ float sW[C * C];
    int t = threadIdx.x;
    for (int i = t; i < C * C; i += 256) sW[i] = W[i];
    __syncthreads();
    int c = t & 63;
    int rbase = blockIdx.x * 64 + (t >> 6);
    for (int it = 0; it < 16; ++it) {
        int row = rbase + it * 4;
        if (row < N) {
            const float* xr = x + (size_t)row * C;
            float acc = 0.f;
#pragma unroll
            for (int k = 0; k < C; ++k) acc = fmaf(xr[k], sW[k * C + c], acc);
            h[(size_t)row * C + c] = acc;
        }
    }
}

// out2 = bias + self-loop term (dinv_i^2 * h_i)
__global__ void init_out2_k(const float* __restrict__ h, const float* __restrict__ dinv,
                            const float* __restrict__ bias, float* __restrict__ out2, int NC) {
    int gid = blockIdx.x * 256 + threadIdx.x;
    if (gid < NC) {
        int i = gid >> 6, c = gid & 63;
        float dv = dinv[i];
        out2[gid] = bias[c] + h[gid] * (dv * dv);
    }
}

// scatter-add messages: 16 threads per edge, float4 each
__global__ void edge_agg_k(const int* __restrict__ ei, const float* __restrict__ h,
                           const float* __restrict__ dinv, float* __restrict__ out2, int E) {
    int gid = blockIdx.x * 256 + threadIdx.x;
    int e = gid >> 4, q = gid & 15;
    if (e < E) {
        int s = ei[e], d = ei[E + e];
        float nm = dinv[s] * dinv[d];
        const float4 hv = *(const float4*)(h + (size_t)s * C + q * 4);
        float* o = out2 + (size_t)d * C + q * 4;
        atomicAdd(o + 0, hv.x * nm);
        atomicAdd(o + 1, hv.y * nm);
        atomicAdd(o + 2, hv.z * nm);
        atomicAdd(o + 3, hv.w * nm);
    }
}

// ---------------- per-graph centroid + its norm ----------------
__global__ void centroid_k(const float* __restrict__ out2, float* __restrict__ cen,
                           float* __restrict__ cnorm) {
    int g = blockIdx.x, t = threadIdx.x;          // 256 threads
    int c = t & 63, p = t >> 6;                   // 4 partials per channel
    const float* base = out2 + (size_t)g * NPG * C;
    float acc = 0.f;
    for (int n = p; n < NPG; n += 4) acc += base[(size_t)n * C + c];
    __shared__ float red[256];
    red[t] = acc;
    __syncthreads();
    if (t < 64) {
        float tot = red[t] + red[64 + t] + red[128 + t] + red[192 + t];
        float m = tot / 1000.0f;
        cen[g * C + t] = m;
        red[t] = m * m;
    }
    __syncthreads();
    if (t < 64) {
        float v = red[t];
        for (int o = 32; o > 0; o >>= 1) v += __shfl_down(v, o, 64);
        if (t == 0) cnorm[g] = sqrtf(v);
    }
}

// cosine similarity of each node row vs its graph centroid
__global__ void score_k(const float* __restrict__ out2, const float* __restrict__ cen,
                        const float* __restrict__ cnorm, float* __restrict__ score, int N) {
    int i = blockIdx.x * 256 + threadIdx.x;
    if (i < N) {
        int g = i / NPG;
        const float4* xr = (const float4*)(out2 + (size_t)i * C);
        const float4* cr = (const float4*)(cen + g * C);
        float num = 0.f, sq = 0.f;
#pragma unroll
        for (int q = 0; q < 16; ++q) {
            float4 a = xr[q], b = cr[q];
            num += a.x * b.x + a.y * b.y + a.z * b.z + a.w * b.w;
            sq  += a.x * a.x + a.y * a.y + a.z * a.z + a.w * a.w;
        }
        float den = sqrtf(sq) * cnorm[g] + 1e-8f;
        score[i] = num / den;
    }
}

// per-graph KL(softmax || uniform)
__global__ void softmax_kl_k(const float* __restrict__ score, float* __restrict__ o_kl) {
    int g = blockIdx.x, t = threadIdx.x;          // 256 threads
    const float* s = score + (size_t)g * NPG;
    __shared__ float red[256];
    float mx = -INFINITY;
    for (int i = t; i < NPG; i += 256) mx = fmaxf(mx, s[i]);
    red[t] = mx;
    __syncthreads();
    for (int w = 128; w > 0; w >>= 1) { if (t < w) red[t] = fmaxf(red[t], red[t + w]); __syncthreads(); }
    mx = red[0];
    __syncthreads();
    float se = 0.f;
    for (int i = t; i < NPG; i += 256) se += expf(s[i] - mx);
    red[t] = se;
    __syncthreads();
    for (int w = 128; w > 0; w >>= 1) { if (t < w) red[t] += red[t + w]; __syncthreads(); }
    float lse = logf(red[0]);
    __syncthreads();
    float kl = 0.f;
    const float ln_npg = 6.9077552790f;           // log(1000) in f32
    for (int i = t; i < NPG; i += 256) {
        float lp = s[i] - mx - lse;
        kl += expf(lp) * (lp + ln_npg);
    }
    red[t] = kl;
    __syncthreads();
    for (int w = 128; w > 0; w >>= 1) { if (t < w) red[t] += red[t + w]; __syncthreads(); }
    if (t == 0) o_kl[g] = red[0];
}

// ---------------- per-graph full descending stable argsort (bitonic, 1024) ----------------
__global__ void sort_k(const float* __restrict__ score, int* __restrict__ sidx,
                       float* __restrict__ o_ind) {
    __shared__ unsigned long long kk[1024];
    int g = blockIdx.x, t = threadIdx.x;          // 512 threads
    for (int i = t; i < 1024; i += 512) {
        unsigned long long v;
        if (i < NPG) {
            unsigned u = __float_as_uint(score[(size_t)g * NPG + i]);
            u = (u & 0x80000000u) ? ~u : (u | 0x80000000u);   // ascending order map
            v = ((unsigned long long)(~u) << 32) | (unsigned)i; // descending score, asc idx
        } else {
            v = ~0ULL;                                          // pad sorts last
        }
        kk[i] = v;
    }
    __syncthreads();
    for (int k = 2; k <= 1024; k <<= 1) {
        for (int j = k >> 1; j > 0; j >>= 1) {
            for (int i = t; i < 1024; i += 512) {
                int ixj = i ^ j;
                if (ixj > i) {
                    unsigned long long a = kk[i], b = kk[ixj];
                    bool up = ((i & k) == 0);
                    if ((a > b) == up) { kk[i] = b; kk[ixj] = a; }
                }
            }
            __syncthreads();
        }
    }
    for (int i = t; i < NPG; i += 512) {
        int idx = (int)(kk[i] & 0xFFFFFFFFULL);
        sidx[(size_t)g * NPG + i] = idx;
        o_ind[(size_t)g * NPG + i] = (float)idx;
    }
}

// ---------------- top-K gather: x_new, perm, batch_new, mapping ----------------
__global__ void topk_k(const int* __restrict__ sidx, const float* __restrict__ score,
                       const float* __restrict__ out2, int* __restrict__ mapping,
                       float* __restrict__ o_xnew, float* __restrict__ o_batch,
                       float* __restrict__ o_perm, int BK) {
    int j = blockIdx.x * 256 + threadIdx.x;
    if (j < BK) {
        int b = j / KTOP, r = j - b * KTOP;
        int node = sidx[(size_t)b * NPG + r];
        int gn = b * NPG + node;
        mapping[gn] = j;
        o_perm[j] = (float)gn;
        o_batch[j] = (float)b;
        float tn = tanhf(score[gn]);
        const float4* src = (const float4*)(out2 + (size_t)gn * C);
        float4* dst = (float4*)(o_xnew + (size_t)j * C);
#pragma unroll
        for (int q = 0; q < 16; ++q) {
            float4 v = src[q];
            v.x *= tn; v.y *= tn; v.z *= tn; v.w *= tn;
            dst[q] = v;
        }
    }
}

// ---------------- edge re-index + mask + attr ----------------
__global__ void edge_out_k(const int* __restrict__ ei, const float* __restrict__ eattr,
                           const int* __restrict__ mapping, float* __restrict__ o_newei,
                           float* __restrict__ o_eattr, float* __restrict__ o_mask, int E) {
    int e = blockIdx.x * 256 + threadIdx.x;
    if (e < E) {
        int m0 = mapping[ei[e]];
        int m1 = mapping[ei[E + e]];
        o_newei[e] = (float)m0;
        o_newei[E + e] = (float)m1;
        bool mk = (m0 >= 0) && (m1 >= 0);
        o_mask[e] = mk ? 1.0f : 0.0f;
        o_eattr[e] = mk ? eattr[e] : 0.0f;
    }
}

extern "C" void kernel_launch(void* const* d_in, const int* in_sizes, int n_in,
                              void* d_out, int out_size, void* d_ws, size_t ws_size,
                              hipStream_t stream) {
    (void)n_in; (void)out_size; (void)ws_size;
    const float* x     = (const float*)d_in[1];
    const int*   ei    = (const int*)d_in[2];
    const float* eattr = (const float*)d_in[3];
    const float* W     = (const float*)d_in[5];
    const float* bias  = (const float*)d_in[6];

    const int N  = in_sizes[1] / C;    // 256000
    const int E  = in_sizes[2] / 2;    // 4096000
    const int B  = N / NPG;            // 256
    const int BK = B * KTOP;           // 128000

    // workspace layout (all offsets 256B-aligned)
    char* wsp = (char*)d_ws;
    float* out2    = (float*)wsp; wsp += (size_t)N * C * 4;   // 65.5 MB
    float* dinv    = (float*)wsp; wsp += (size_t)N * 4;
    float* score   = (float*)wsp; wsp += (size_t)N * 4;
    float* cen     = (float*)wsp; wsp += (size_t)B * C * 4;
    float* cnorm   = (float*)wsp; wsp += 1024;                // B*4
    int*   sidx    = (int*)wsp;   wsp += (size_t)B * NPG * 4;
    int*   mapping = (int*)wsp;   wsp += (size_t)N * 4;
    int*   deg     = (int*)wsp;   wsp += (size_t)N * 4;

    // output layout (flat f32, reference return order)
    float* out     = (float*)d_out;
    float* o_xnew  = out;                                   // BK*C
    float* o_newei = o_xnew + (size_t)BK * C;               // 2E
    float* o_eattr = o_newei + 2 * (size_t)E;               // E
    float* o_mask  = o_eattr + (size_t)E;                   // E
    float* o_batch = o_mask + (size_t)E;                    // BK
    float* o_perm  = o_batch + (size_t)BK;                  // BK
    float* o_kl    = o_perm + (size_t)BK;                   // B
    float* o_ind   = o_kl + (size_t)B;                      // B*NPG

    // h buffer reuses the front of d_out (N*C floats); dead before outputs written
    float* hbuf = out;

    hipMemsetAsync(deg, 0, (size_t)N * 4, stream);
    hipMemsetAsync(mapping, 0xFF, (size_t)N * 4, stream);   // -1

    deg_count_k<<<(E + 255) / 256, 256, 0, stream>>>(ei, deg, E);
    dinv_k<<<(N + 255) / 256, 256, 0, stream>>>(deg, dinv, N);
    gemm_k<<<(N + 63) / 64, 256, 0, stream>>>(x, W, hbuf, N);
    init_out2_k<<<(N * C + 255) / 256, 256, 0, stream>>>(hbuf, dinv, bias, out2, N * C);
    edge_agg_k<<<(int)(((size_t)E * 16 + 255) / 256), 256, 0, stream>>>(ei, hbuf, dinv, out2, E);
    centroid_k<<<B, 256, 0, stream>>>(out2, cen, cnorm);
    score_k<<<(N + 255) / 256, 256, 0, stream>>>(out2, cen, cnorm, score, N);
    softmax_kl_k<<<B, 256, 0, stream>>>(score, o_kl);
    sort_k<<<B, 512, 0, stream>>>(score, sidx, o_ind);
    topk_k<<<(BK + 255) / 256, 256, 0, stream>>>(sidx, score, out2, mapping,
                                                 o_xnew, o_batch, o_perm, BK);
    edge_out_k<<<(E + 255) / 256, 256, 0, stream>>>(ei, eattr, mapping,
                                                    o_newei, o_eattr, o_mask, E);
}

// Round 2
// 865.093 us; speedup vs baseline: 4.6640x; 4.6640x over previous
//
#include <hip/hip_runtime.h>
#include <math.h>

#define NPG 1000
#define KTOP 500
#define C 64
#define EPG 16000   // edges per graph = NPG * DEG

// ---------------- degree count (in-degree over dst) ----------------
__global__ void deg_count_k(const int* __restrict__ ei, int* __restrict__ deg, int E) {
    int e = blockIdx.x * 256 + threadIdx.x;
    if (e < E) atomicAdd(&deg[ei[E + e]], 1);
}

// dinv = 1/sqrt(deg+1)   (+1 = self loop; matches ref rsqrt(count incl self-loop))
__global__ void dinv_k(const int* __restrict__ deg, float* __restrict__ dinv, int N) {
    int i = blockIdx.x * 256 + threadIdx.x;
    if (i < N) dinv[i] = 1.0f / sqrtf((float)(deg[i] + 1));
}

// ---------------- per-graph exclusive scan of deg -> CSR offsets + cursor copy ----------------
__global__ void scan_k(const int* __restrict__ deg, int* __restrict__ off,
                       int* __restrict__ cursor) {
    int g = blockIdx.x, t = threadIdx.x;          // 256 threads
    const int* dg = deg + (size_t)g * NPG;
    int base = t * 4;
    int v0 = 0, v1 = 0, v2 = 0, v3 = 0;
    if (base + 0 < NPG) v0 = dg[base + 0];
    if (base + 1 < NPG) v1 = dg[base + 1];
    if (base + 2 < NPG) v2 = dg[base + 2];
    if (base + 3 < NPG) v3 = dg[base + 3];
    int s = v0 + v1 + v2 + v3;
    __shared__ int red[256];
    red[t] = s;
    __syncthreads();
    for (int o = 1; o < 256; o <<= 1) {
        int x = (t >= o) ? red[t - o] : 0;
        __syncthreads();
        red[t] += x;
        __syncthreads();
    }
    int excl = red[t] - s;                        // exclusive prefix of this 4-chunk
    int gb = g * EPG;
    int p = gb + excl;
    if (base + 0 < NPG) { off[(size_t)g * NPG + base + 0] = p; cursor[(size_t)g * NPG + base + 0] = p; p += v0; }
    if (base + 1 < NPG) { off[(size_t)g * NPG + base + 1] = p; cursor[(size_t)g * NPG + base + 1] = p; p += v1; }
    if (base + 2 < NPG) { off[(size_t)g * NPG + base + 2] = p; cursor[(size_t)g * NPG + base + 2] = p; p += v2; }
    if (base + 3 < NPG) { off[(size_t)g * NPG + base + 3] = p; cursor[(size_t)g * NPG + base + 3] = p; p += v3; }
}

// ---------------- CSR fill: csr[pos] = src for edges grouped by dst ----------------
__global__ void csr_fill_k(const int* __restrict__ ei, int* __restrict__ cursor,
                           int* __restrict__ csr, int E) {
    int e = blockIdx.x * 256 + threadIdx.x;
    if (e < E) {
        int s = ei[e], d = ei[E + e];
        int p = atomicAdd(&cursor[d], 1);
        csr[p] = s;
    }
}

// ---------------- h = x @ W  (N x 64 @ 64 x 64) ----------------
__global__ void gemm_k(const float* __restrict__ x, const float* __restrict__ W,
                       float* __restrict__ h, int N) {
    __shared__ float sW[C * C];
    int t = threadIdx.x;
    for (int i = t; i < C * C; i += 256) sW[i] = W[i];
    __syncthreads();
    int c = t & 63;
    int rbase = blockIdx.x * 64 + (t >> 6);
    for (int it = 0; it < 16; ++it) {
        int row = rbase + it * 4;
        if (row < N) {
            const float* xr = x + (size_t)row * C;
            float acc = 0.f;
#pragma unroll
            for (int k = 0; k < C; ++k) acc = fmaf(xr[k], sW[k * C + c], acc);
            h[(size_t)row * C + c] = acc;
        }
    }
}

// ---------------- gather aggregation: one wave per node, lane = channel ----------------
// out2[i] = bias + dinv_i * sum_j(h[src_j]*dinv[src_j]) + dinv_i^2 * h[i]
__global__ void gather_k(const int* __restrict__ csr, const int* __restrict__ off,
                         const int* __restrict__ deg, const float* __restrict__ h,
                         const float* __restrict__ dinv, const float* __restrict__ bias,
                         float* __restrict__ out2, int N) {
    int node = blockIdx.x * 4 + (threadIdx.x >> 6);
    int c = threadIdx.x & 63;
    if (node < N) {
        int o0 = off[node], dg = deg[node];
        float acc = 0.f;
        int j = 0;
        for (; j + 4 <= dg; j += 4) {
            int s0 = csr[o0 + j + 0];
            int s1 = csr[o0 + j + 1];
            int s2 = csr[o0 + j + 2];
            int s3 = csr[o0 + j + 3];
            float w0 = dinv[s0], w1 = dinv[s1], w2 = dinv[s2], w3 = dinv[s3];
            acc = fmaf(h[(size_t)s0 * C + c], w0, acc);
            acc = fmaf(h[(size_t)s1 * C + c], w1, acc);
            acc = fmaf(h[(size_t)s2 * C + c], w2, acc);
            acc = fmaf(h[(size_t)s3 * C + c], w3, acc);
        }
        for (; j < dg; ++j) {
            int s = csr[o0 + j];
            acc = fmaf(h[(size_t)s * C + c], dinv[s], acc);
        }
        float di = dinv[node];
        float hv = h[(size_t)node * C + c];
        out2[(size_t)node * C + c] = bias[c] + di * acc + di * di * hv;
    }
}

// ---------------- per-graph centroid + its norm ----------------
__global__ void centroid_k(const float* __restrict__ out2, float* __restrict__ cen,
                           float* __restrict__ cnorm) {
    int g = blockIdx.x, t = threadIdx.x;          // 256 threads
    int c = t & 63, p = t >> 6;                   // 4 partials per channel
    const float* base = out2 + (size_t)g * NPG * C;
    float acc = 0.f;
    for (int n = p; n < NPG; n += 4) acc += base[(size_t)n * C + c];
    __shared__ float red[256];
    red[t] = acc;
    __syncthreads();
    if (t < 64) {
        float tot = red[t] + red[64 + t] + red[128 + t] + red[192 + t];
        float m = tot / 1000.0f;
        cen[g * C + t] = m;
        red[t] = m * m;
    }
    __syncthreads();
    if (t < 64) {
        float v = red[t];
        for (int o = 32; o > 0; o >>= 1) v += __shfl_down(v, o, 64);
        if (t == 0) cnorm[g] = sqrtf(v);
    }
}

// cosine similarity of each node row vs its graph centroid
__global__ void score_k(const float* __restrict__ out2, const float* __restrict__ cen,
                        const float* __restrict__ cnorm, float* __restrict__ score, int N) {
    int i = blockIdx.x * 256 + threadIdx.x;
    if (i < N) {
        int g = i / NPG;
        const float4* xr = (const float4*)(out2 + (size_t)i * C);
        const float4* cr = (const float4*)(cen + g * C);
        float num = 0.f, sq = 0.f;
#pragma unroll
        for (int q = 0; q < 16; ++q) {
            float4 a = xr[q], b = cr[q];
            num += a.x * b.x + a.y * b.y + a.z * b.z + a.w * b.w;
            sq  += a.x * a.x + a.y * a.y + a.z * a.z + a.w * a.w;
        }
        float den = sqrtf(sq) * cnorm[g] + 1e-8f;
        score[i] = num / den;
    }
}

// per-graph KL(softmax || uniform)
__global__ void softmax_kl_k(const float* __restrict__ score, float* __restrict__ o_kl) {
    int g = blockIdx.x, t = threadIdx.x;          // 256 threads
    const float* s = score + (size_t)g * NPG;
    __shared__ float red[256];
    float mx = -INFINITY;
    for (int i = t; i < NPG; i += 256) mx = fmaxf(mx, s[i]);
    red[t] = mx;
    __syncthreads();
    for (int w = 128; w > 0; w >>= 1) { if (t < w) red[t] = fmaxf(red[t], red[t + w]); __syncthreads(); }
    mx = red[0];
    __syncthreads();
    float se = 0.f;
    for (int i = t; i < NPG; i += 256) se += expf(s[i] - mx);
    red[t] = se;
    __syncthreads();
    for (int w = 128; w > 0; w >>= 1) { if (t < w) red[t] += red[t + w]; __syncthreads(); }
    float lse = logf(red[0]);
    __syncthreads();
    float kl = 0.f;
    const float ln_npg = 6.9077552790f;           // log(1000) in f32
    for (int i = t; i < NPG; i += 256) {
        float lp = s[i] - mx - lse;
        kl += expf(lp) * (lp + ln_npg);
    }
    red[t] = kl;
    __syncthreads();
    for (int w = 128; w > 0; w >>= 1) { if (t < w) red[t] += red[t + w]; __syncthreads(); }
    if (t == 0) o_kl[g] = red[0];
}

// ---------------- per-graph full descending stable argsort (bitonic, 1024) ----------------
__global__ void sort_k(const float* __restrict__ score, int* __restrict__ sidx,
                       float* __restrict__ o_ind) {
    __shared__ unsigned long long kk[1024];
    int g = blockIdx.x, t = threadIdx.x;          // 512 threads
    for (int i = t; i < 1024; i += 512) {
        unsigned long long v;
        if (i < NPG) {
            unsigned u = __float_as_uint(score[(size_t)g * NPG + i]);
            u = (u & 0x80000000u) ? ~u : (u | 0x80000000u);     // ascending order map
            v = ((unsigned long long)(~u) << 32) | (unsigned)i; // descending score, asc idx
        } else {
            v = ~0ULL;                                          // pad sorts last
        }
        kk[i] = v;
    }
    __syncthreads();
    for (int k = 2; k <= 1024; k <<= 1) {
        for (int j = k >> 1; j > 0; j >>= 1) {
            for (int i = t; i < 1024; i += 512) {
                int ixj = i ^ j;
                if (ixj > i) {
                    unsigned long long a = kk[i], b = kk[ixj];
                    bool up = ((i & k) == 0);
                    if ((a > b) == up) { kk[i] = b; kk[ixj] = a; }
                }
            }
            __syncthreads();
        }
    }
    for (int i = t; i < NPG; i += 512) {
        int idx = (int)(kk[i] & 0xFFFFFFFFULL);
        sidx[(size_t)g * NPG + i] = idx;
        o_ind[(size_t)g * NPG + i] = (float)idx;
    }
}

// ---------------- top-K gather: x_new, perm, batch_new, mapping ----------------
__global__ void topk_k(const int* __restrict__ sidx, const float* __restrict__ score,
                       const float* __restrict__ out2, int* __restrict__ mapping,
                       float* __restrict__ o_xnew, float* __restrict__ o_batch,
                       float* __restrict__ o_perm, int BK) {
    int j = blockIdx.x * 256 + threadIdx.x;
    if (j < BK) {
        int b = j / KTOP, r = j - b * KTOP;
        int node = sidx[(size_t)b * NPG + r];
        int gn = b * NPG + node;
        mapping[gn] = j;
        o_perm[j] = (float)gn;
        o_batch[j] = (float)b;
        float tn = tanhf(score[gn]);
        const float4* src = (const float4*)(out2 + (size_t)gn * C);
        float4* dst = (float4*)(o_xnew + (size_t)j * C);
#pragma unroll
        for (int q = 0; q < 16; ++q) {
            float4 v = src[q];
            v.x *= tn; v.y *= tn; v.z *= tn; v.w *= tn;
            dst[q] = v;
        }
    }
}

// ---------------- edge re-index + mask + attr ----------------
__global__ void edge_out_k(const int* __restrict__ ei, const float* __restrict__ eattr,
                           const int* __restrict__ mapping, float* __restrict__ o_newei,
                           float* __restrict__ o_eattr, float* __restrict__ o_mask, int E) {
    int e = blockIdx.x * 256 + threadIdx.x;
    if (e < E) {
        int m0 = mapping[ei[e]];
        int m1 = mapping[ei[E + e]];
        o_newei[e] = (float)m0;
        o_newei[E + e] = (float)m1;
        bool mk = (m0 >= 0) && (m1 >= 0);
        o_mask[e] = mk ? 1.0f : 0.0f;
        o_eattr[e] = mk ? eattr[e] : 0.0f;
    }
}

extern "C" void kernel_launch(void* const* d_in, const int* in_sizes, int n_in,
                              void* d_out, int out_size, void* d_ws, size_t ws_size,
                              hipStream_t stream) {
    (void)n_in; (void)out_size; (void)ws_size;
    const float* x     = (const float*)d_in[1];
    const int*   ei    = (const int*)d_in[2];
    const float* eattr = (const float*)d_in[3];
    const float* W     = (const float*)d_in[5];
    const float* bias  = (const float*)d_in[6];

    const int N  = in_sizes[1] / C;    // 256000
    const int E  = in_sizes[2] / 2;    // 4096000
    const int B  = N / NPG;            // 256
    const int BK = B * KTOP;           // 128000

    // workspace layout
    char* wsp = (char*)d_ws;
    float* out2    = (float*)wsp; wsp += (size_t)N * C * 4;   // 65.5 MB
    float* dinv    = (float*)wsp; wsp += (size_t)N * 4;
    float* score   = (float*)wsp; wsp += (size_t)N * 4;
    float* cen     = (float*)wsp; wsp += (size_t)B * C * 4;
    float* cnorm   = (float*)wsp; wsp += 1024;                // B*4
    int*   sidx    = (int*)wsp;   wsp += (size_t)B * NPG * 4;
    int*   mapping = (int*)wsp;   wsp += (size_t)N * 4;
    int*   deg     = (int*)wsp;   wsp += (size_t)N * 4;
    int*   off     = (int*)wsp;   wsp += (size_t)N * 4;
    int*   cursor  = (int*)wsp;   wsp += (size_t)N * 4;

    // output layout (flat f32, reference return order)
    float* out     = (float*)d_out;
    float* o_xnew  = out;                                   // BK*C   (8.192M)
    float* o_newei = o_xnew + (size_t)BK * C;               // 2E     (8.192M)
    float* o_eattr = o_newei + 2 * (size_t)E;               // E      (4.096M)
    float* o_mask  = o_eattr + (size_t)E;                   // E      (4.096M)
    float* o_batch = o_mask + (size_t)E;                    // BK
    float* o_perm  = o_batch + (size_t)BK;                  // BK
    float* o_kl    = o_perm + (size_t)BK;                   // B
    float* o_ind   = o_kl + (size_t)B;                      // B*NPG

    // scratch aliased onto d_out (dead before those outputs are written):
    //   hbuf = first N*C floats (covers o_xnew + o_newei exactly)
    //   csr  = E ints in the o_eattr region
    float* hbuf = out;
    int*   csr  = (int*)o_eattr;

    hipMemsetAsync(deg, 0, (size_t)N * 4, stream);
    hipMemsetAsync(mapping, 0xFF, (size_t)N * 4, stream);   // -1

    deg_count_k<<<(E + 255) / 256, 256, 0, stream>>>(ei, deg, E);
    dinv_k<<<(N + 255) / 256, 256, 0, stream>>>(deg, dinv, N);
    scan_k<<<B, 256, 0, stream>>>(deg, off, cursor);
    csr_fill_k<<<(E + 255) / 256, 256, 0, stream>>>(ei, cursor, csr, E);
    gemm_k<<<(N + 63) / 64, 256, 0, stream>>>(x, W, hbuf, N);
    gather_k<<<(N + 3) / 4, 256, 0, stream>>>(csr, off, deg, hbuf, dinv, bias, out2, N);
    centroid_k<<<B, 256, 0, stream>>>(out2, cen, cnorm);
    score_k<<<(N + 255) / 256, 256, 0, stream>>>(out2, cen, cnorm, score, N);
    softmax_kl_k<<<B, 256, 0, stream>>>(score, o_kl);
    sort_k<<<B, 512, 0, stream>>>(score, sidx, o_ind);
    topk_k<<<(BK + 255) / 256, 256, 0, stream>>>(sidx, score, out2, mapping,
                                                 o_xnew, o_batch, o_perm, BK);
    edge_out_k<<<(E + 255) / 256, 256, 0, stream>>>(ei, eattr, mapping,
                                                    o_newei, o_eattr, o_mask, E);
}

// Round 3
// 735.277 us; speedup vs baseline: 5.4875x; 1.1766x over previous
//
#include <hip/hip_runtime.h>
#include <math.h>

#define NPG 1000
#define KTOP 500
#define C 64
#define EPG 16000   // edges per graph = NPG * DEG

// ---------------- degree count (in-degree over dst) ----------------
__global__ void deg_count_k(const int* __restrict__ ei, int* __restrict__ deg, int E) {
    int e = blockIdx.x * 256 + threadIdx.x;
    if (e < E) atomicAdd(&deg[ei[E + e]], 1);
}

// dinv = 1/sqrt(deg+1)   (+1 = self loop)
__global__ void dinv_k(const int* __restrict__ deg, float* __restrict__ dinv, int N) {
    int i = blockIdx.x * 256 + threadIdx.x;
    if (i < N) dinv[i] = 1.0f / sqrtf((float)(deg[i] + 1));
}

// ---------------- per-graph exclusive scan of deg -> CSR offsets + cursor copy ----------------
__global__ void scan_k(const int* __restrict__ deg, int* __restrict__ off,
                       int* __restrict__ cursor) {
    int g = blockIdx.x, t = threadIdx.x;          // 256 threads
    const int* dg = deg + (size_t)g * NPG;
    int base = t * 4;
    int v0 = 0, v1 = 0, v2 = 0, v3 = 0;
    if (base + 0 < NPG) v0 = dg[base + 0];
    if (base + 1 < NPG) v1 = dg[base + 1];
    if (base + 2 < NPG) v2 = dg[base + 2];
    if (base + 3 < NPG) v3 = dg[base + 3];
    int s = v0 + v1 + v2 + v3;
    __shared__ int red[256];
    red[t] = s;
    __syncthreads();
    for (int o = 1; o < 256; o <<= 1) {
        int x = (t >= o) ? red[t - o] : 0;
        __syncthreads();
        red[t] += x;
        __syncthreads();
    }
    int excl = red[t] - s;
    int gb = g * EPG;
    int p = gb + excl;
    if (base + 0 < NPG) { off[(size_t)g * NPG + base + 0] = p; cursor[(size_t)g * NPG + base + 0] = p; p += v0; }
    if (base + 1 < NPG) { off[(size_t)g * NPG + base + 1] = p; cursor[(size_t)g * NPG + base + 1] = p; p += v1; }
    if (base + 2 < NPG) { off[(size_t)g * NPG + base + 2] = p; cursor[(size_t)g * NPG + base + 2] = p; p += v2; }
    if (base + 3 < NPG) { off[(size_t)g * NPG + base + 3] = p; cursor[(size_t)g * NPG + base + 3] = p; p += v3; }
}

// ---------------- CSR fill: csr[pos] = src for edges grouped by dst ----------------
__global__ void csr_fill_k(const int* __restrict__ ei, int* __restrict__ cursor,
                           int* __restrict__ csr, int E) {
    int e = blockIdx.x * 256 + threadIdx.x;
    if (e < E) {
        int s = ei[e], d = ei[E + e];
        int p = atomicAdd(&cursor[d], 1);
        csr[p] = s;
    }
}

// ---------------- h = x @ W : register-tiled, 2 rows/thread, W in LDS ----------------
__global__ __launch_bounds__(256) void gemm_k(const float* __restrict__ x,
                                              const float* __restrict__ W,
                                              float* __restrict__ h, int N) {
    __shared__ float sW[C * C];
    int t = threadIdx.x;
    for (int i = t; i < C * C / 4; i += 256) ((float4*)sW)[i] = ((const float4*)W)[i];
    __syncthreads();
    int r0 = blockIdx.x * 512 + t;
    int r1 = r0 + 256;
    if (r0 >= N) return;
    bool has1 = (r1 < N);
    const float4* x0 = (const float4*)(x + (size_t)r0 * C);
    const float4* x1 = (const float4*)(x + (size_t)(has1 ? r1 : r0) * C);
    float acc0[C], acc1[C];
#pragma unroll
    for (int i = 0; i < C; ++i) { acc0[i] = 0.f; acc1[i] = 0.f; }
    float4 a0 = x0[0], a1 = x1[0];
    for (int k4 = 0; k4 < 16; ++k4) {
        float4 b0, b1;
        if (k4 < 15) { b0 = x0[k4 + 1]; b1 = x1[k4 + 1]; }
        const float4* wr = (const float4*)(sW + k4 * 4 * C);
        const float* a0f = (const float*)&a0;
        const float* a1f = (const float*)&a1;
#pragma unroll
        for (int c4 = 0; c4 < 16; ++c4) {
            float4 w[4];
            w[0] = wr[c4]; w[1] = wr[16 + c4]; w[2] = wr[32 + c4]; w[3] = wr[48 + c4];
            const float* wf = (const float*)w;
#pragma unroll
            for (int j = 0; j < 4; ++j) {
                float s0 = acc0[c4 * 4 + j], s1 = acc1[c4 * 4 + j];
#pragma unroll
                for (int kk = 0; kk < 4; ++kk) {
                    float wv = wf[kk * 4 + j];
                    s0 = fmaf(a0f[kk], wv, s0);
                    s1 = fmaf(a1f[kk], wv, s1);
                }
                acc0[c4 * 4 + j] = s0; acc1[c4 * 4 + j] = s1;
            }
        }
        a0 = b0; a1 = b1;
    }
    float4* h0 = (float4*)(h + (size_t)r0 * C);
#pragma unroll
    for (int q = 0; q < 16; ++q) h0[q] = ((float4*)acc0)[q];
    if (has1) {
        float4* h1 = (float4*)(h + (size_t)r1 * C);
#pragma unroll
        for (int q = 0; q < 16; ++q) h1[q] = ((float4*)acc1)[q];
    }
}

// ---------------- gather aggregation: one wave per node, lane = channel ----------------
__global__ void gather_k(const int* __restrict__ csr, const int* __restrict__ off,
                         const int* __restrict__ deg, const float* __restrict__ h,
                         const float* __restrict__ dinv, const float* __restrict__ bias,
                         float* __restrict__ out2, int N) {
    int node = blockIdx.x * 4 + (threadIdx.x >> 6);
    int c = threadIdx.x & 63;
    if (node < N) {
        int o0 = off[node], dg = deg[node];
        float acc = 0.f;
        int j = 0;
        for (; j + 4 <= dg; j += 4) {
            int s0 = csr[o0 + j + 0];
            int s1 = csr[o0 + j + 1];
            int s2 = csr[o0 + j + 2];
            int s3 = csr[o0 + j + 3];
            float w0 = dinv[s0], w1 = dinv[s1], w2 = dinv[s2], w3 = dinv[s3];
            acc = fmaf(h[(size_t)s0 * C + c], w0, acc);
            acc = fmaf(h[(size_t)s1 * C + c], w1, acc);
            acc = fmaf(h[(size_t)s2 * C + c], w2, acc);
            acc = fmaf(h[(size_t)s3 * C + c], w3, acc);
        }
        for (; j < dg; ++j) {
            int s = csr[o0 + j];
            acc = fmaf(h[(size_t)s * C + c], dinv[s], acc);
        }
        float di = dinv[node];
        float hv = h[(size_t)node * C + c];
        out2[(size_t)node * C + c] = bias[c] + di * acc + di * di * hv;
    }
}

// ---------------- per-graph centroid: partial sums (4 blocks/graph) + finalize ----------------
__global__ void centroid_part_k(const float* __restrict__ out2, float* __restrict__ pcen) {
    int blk = blockIdx.x;            // g*4 + p
    int g = blk >> 2, p = blk & 3;
    int t = threadIdx.x;             // 256
    int c = t & 63, q = t >> 6;
    const float* base = out2 + (size_t)g * NPG * C;
    int n0 = p * 250, n1 = n0 + 250;
    float acc = 0.f;
    for (int n = n0 + q; n < n1; n += 4) acc += base[(size_t)n * C + c];
    __shared__ float red[256];
    red[t] = acc;
    __syncthreads();
    if (t < 64) pcen[(size_t)blk * C + t] = red[t] + red[64 + t] + red[128 + t] + red[192 + t];
}

__global__ void cen_fin_k(const float* __restrict__ pcen, float* __restrict__ cen,
                          float* __restrict__ cnorm) {
    int g = blockIdx.x, c = threadIdx.x;   // 64 threads
    float s = pcen[(size_t)(g * 4 + 0) * C + c] + pcen[(size_t)(g * 4 + 1) * C + c]
            + pcen[(size_t)(g * 4 + 2) * C + c] + pcen[(size_t)(g * 4 + 3) * C + c];
    float m = s / 1000.0f;
    cen[g * C + c] = m;
    float v = m * m;
    for (int o = 32; o > 0; o >>= 1) v += __shfl_down(v, o, 64);
    if (c == 0) cnorm[g] = sqrtf(v);
}

// cosine similarity of each node row vs its graph centroid
__global__ void score_k(const float* __restrict__ out2, const float* __restrict__ cen,
                        const float* __restrict__ cnorm, float* __restrict__ score, int N) {
    int i = blockIdx.x * 256 + threadIdx.x;
    if (i < N) {
        int g = i / NPG;
        const float4* xr = (const float4*)(out2 + (size_t)i * C);
        const float4* cr = (const float4*)(cen + g * C);
        float num = 0.f, sq = 0.f;
#pragma unroll
        for (int q = 0; q < 16; ++q) {
            float4 a = xr[q], b = cr[q];
            num += a.x * b.x + a.y * b.y + a.z * b.z + a.w * b.w;
            sq  += a.x * a.x + a.y * a.y + a.z * a.z + a.w * a.w;
        }
        float den = sqrtf(sq) * cnorm[g] + 1e-8f;
        score[i] = num / den;
    }
}

// per-graph KL(softmax || uniform)
__global__ void softmax_kl_k(const float* __restrict__ score, float* __restrict__ o_kl) {
    int g = blockIdx.x, t = threadIdx.x;          // 256 threads
    const float* s = score + (size_t)g * NPG;
    __shared__ float red[256];
    float mx = -INFINITY;
    for (int i = t; i < NPG; i += 256) mx = fmaxf(mx, s[i]);
    red[t] = mx;
    __syncthreads();
    for (int w = 128; w > 0; w >>= 1) { if (t < w) red[t] = fmaxf(red[t], red[t + w]); __syncthreads(); }
    mx = red[0];
    __syncthreads();
    float se = 0.f;
    for (int i = t; i < NPG; i += 256) se += expf(s[i] - mx);
    red[t] = se;
    __syncthreads();
    for (int w = 128; w > 0; w >>= 1) { if (t < w) red[t] += red[t + w]; __syncthreads(); }
    float lse = logf(red[0]);
    __syncthreads();
    float kl = 0.f;
    const float ln_npg = 6.9077552790f;           // log(1000) in f32
    for (int i = t; i < NPG; i += 256) {
        float lp = s[i] - mx - lse;
        kl += expf(lp) * (lp + ln_npg);
    }
    red[t] = kl;
    __syncthreads();
    for (int w = 128; w > 0; w >>= 1) { if (t < w) red[t] += red[t + w]; __syncthreads(); }
    if (t == 0) o_kl[g] = red[0];
}

// ---------------- per-graph full descending stable argsort (bitonic, 1024) ----------------
__global__ void sort_k(const float* __restrict__ score, int* __restrict__ sidx,
                       float* __restrict__ o_ind) {
    __shared__ unsigned long long kk[1024];
    int g = blockIdx.x, t = threadIdx.x;          // 512 threads
    for (int i = t; i < 1024; i += 512) {
        unsigned long long v;
        if (i < NPG) {
            unsigned u = __float_as_uint(score[(size_t)g * NPG + i]);
            u = (u & 0x80000000u) ? ~u : (u | 0x80000000u);     // ascending order map
            v = ((unsigned long long)(~u) << 32) | (unsigned)i; // descending score, asc idx
        } else {
            v = ~0ULL;
        }
        kk[i] = v;
    }
    __syncthreads();
    for (int k = 2; k <= 1024; k <<= 1) {
        for (int j = k >> 1; j > 0; j >>= 1) {
            for (int i = t; i < 1024; i += 512) {
                int ixj = i ^ j;
                if (ixj > i) {
                    unsigned long long a = kk[i], b = kk[ixj];
                    bool up = ((i & k) == 0);
                    if ((a > b) == up) { kk[i] = b; kk[ixj] = a; }
                }
            }
            __syncthreads();
        }
    }
    for (int i = t; i < NPG; i += 512) {
        int idx = (int)(kk[i] & 0xFFFFFFFFULL);
        sidx[(size_t)g * NPG + i] = idx;
        o_ind[(size_t)g * NPG + i] = (float)idx;
    }
}

// ---------------- top-K gather: x_new, perm, batch_new, mapping ----------------
__global__ void topk_k(const int* __restrict__ sidx, const float* __restrict__ score,
                       const float* __restrict__ out2, int* __restrict__ mapping,
                       float* __restrict__ o_xnew, float* __restrict__ o_batch,
                       float* __restrict__ o_perm, int BK) {
    int j = blockIdx.x * 256 + threadIdx.x;
    if (j < BK) {
        int b = j / KTOP, r = j - b * KTOP;
        int node = sidx[(size_t)b * NPG + r];
        int gn = b * NPG + node;
        mapping[gn] = j;
        o_perm[j] = (float)gn;
        o_batch[j] = (float)b;
        float tn = tanhf(score[gn]);
        const float4* src = (const float4*)(out2 + (size_t)gn * C);
        float4* dst = (float4*)(o_xnew + (size_t)j * C);
#pragma unroll
        for (int q = 0; q < 16; ++q) {
            float4 v = src[q];
            v.x *= tn; v.y *= tn; v.z *= tn; v.w *= tn;
            dst[q] = v;
        }
    }
}

// ---------------- edge re-index + mask + attr ----------------
__global__ void edge_out_k(const int* __restrict__ ei, const float* __restrict__ eattr,
                           const int* __restrict__ mapping, float* __restrict__ o_newei,
                           float* __restrict__ o_eattr, float* __restrict__ o_mask, int E) {
    int e = blockIdx.x * 256 + threadIdx.x;
    if (e < E) {
        int m0 = mapping[ei[e]];
        int m1 = mapping[ei[E + e]];
        o_newei[e] = (float)m0;
        o_newei[E + e] = (float)m1;
        bool mk = (m0 >= 0) && (m1 >= 0);
        o_mask[e] = mk ? 1.0f : 0.0f;
        o_eattr[e] = mk ? eattr[e] : 0.0f;
    }
}

extern "C" void kernel_launch(void* const* d_in, const int* in_sizes, int n_in,
                              void* d_out, int out_size, void* d_ws, size_t ws_size,
                              hipStream_t stream) {
    (void)n_in; (void)out_size; (void)ws_size;
    const float* x     = (const float*)d_in[1];
    const int*   ei    = (const int*)d_in[2];
    const float* eattr = (const float*)d_in[3];
    const float* W     = (const float*)d_in[5];
    const float* bias  = (const float*)d_in[6];

    const int N  = in_sizes[1] / C;    // 256000
    const int E  = in_sizes[2] / 2;    // 4096000
    const int B  = N / NPG;            // 256
    const int BK = B * KTOP;           // 128000

    // workspace layout
    char* wsp = (char*)d_ws;
    float* out2    = (float*)wsp; wsp += (size_t)N * C * 4;   // 65.5 MB
    float* dinv    = (float*)wsp; wsp += (size_t)N * 4;
    float* score   = (float*)wsp; wsp += (size_t)N * 4;
    float* cen     = (float*)wsp; wsp += (size_t)B * C * 4;
    float* cnorm   = (float*)wsp; wsp += 1024;                // B*4
    int*   sidx    = (int*)wsp;   wsp += (size_t)B * NPG * 4;
    int*   mapping = (int*)wsp;   wsp += (size_t)N * 4;
    int*   deg     = (int*)wsp;   wsp += (size_t)N * 4;
    int*   off     = (int*)wsp;   wsp += (size_t)N * 4;
    int*   cursor  = (int*)wsp;   wsp += (size_t)N * 4;
    float* pcen    = (float*)wsp; wsp += (size_t)B * 4 * C * 4;

    // output layout (flat f32, reference return order)
    float* out     = (float*)d_out;
    float* o_xnew  = out;                                   // BK*C
    float* o_newei = o_xnew + (size_t)BK * C;               // 2E
    float* o_eattr = o_newei + 2 * (size_t)E;               // E
    float* o_mask  = o_eattr + (size_t)E;                   // E
    float* o_batch = o_mask + (size_t)E;                    // BK
    float* o_perm  = o_batch + (size_t)BK;                  // BK
    float* o_kl    = o_perm + (size_t)BK;                   // B
    float* o_ind   = o_kl + (size_t)B;                      // B*NPG

    // scratch aliased onto d_out (dead before those outputs are written)
    float* hbuf = out;                 // N*C floats
    int*   csr  = (int*)o_eattr;       // E ints

    hipMemsetAsync(deg, 0, (size_t)N * 4, stream);
    hipMemsetAsync(mapping, 0xFF, (size_t)N * 4, stream);   // -1

    deg_count_k<<<(E + 255) / 256, 256, 0, stream>>>(ei, deg, E);
    dinv_k<<<(N + 255) / 256, 256, 0, stream>>>(deg, dinv, N);
    scan_k<<<B, 256, 0, stream>>>(deg, off, cursor);
    csr_fill_k<<<(E + 255) / 256, 256, 0, stream>>>(ei, cursor, csr, E);
    gemm_k<<<(N + 511) / 512, 256, 0, stream>>>(x, W, hbuf, N);
    gather_k<<<(N + 3) / 4, 256, 0, stream>>>(csr, off, deg, hbuf, dinv, bias, out2, N);
    centroid_part_k<<<B * 4, 256, 0, stream>>>(out2, pcen);
    cen_fin_k<<<B, 64, 0, stream>>>(pcen, cen, cnorm);
    score_k<<<(N + 255) / 256, 256, 0, stream>>>(out2, cen, cnorm, score, N);
    softmax_kl_k<<<B, 256, 0, stream>>>(score, o_kl);
    sort_k<<<B, 512, 0, stream>>>(score, sidx, o_ind);
    topk_k<<<(BK + 255) / 256, 256, 0, stream>>>(sidx, score, out2, mapping,
                                                 o_xnew, o_batch, o_perm, BK);
    edge_out_k<<<(E + 255) / 256, 256, 0, stream>>>(ei, eattr, mapping,
                                                    o_newei, o_eattr, o_mask, E);
}

// Round 4
// 678.103 us; speedup vs baseline: 5.9502x; 1.0843x over previous
//
#include <hip/hip_runtime.h>
#include <math.h>

#define NPG 1000
#define KTOP 500
#define C 64
#define EPG 16000   // edges per graph = NPG * DEG

// ---------------- degree count (in-degree over dst) ----------------
__global__ void deg_count_k(const int* __restrict__ ei, int* __restrict__ deg, int E) {
    int e = blockIdx.x * 256 + threadIdx.x;
    if (e < E) atomicAdd(&deg[ei[E + e]], 1);
}

// dinv = 1/sqrt(deg+1)   (+1 = self loop)
__global__ void dinv_k(const int* __restrict__ deg, float* __restrict__ dinv, int N) {
    int i = blockIdx.x * 256 + threadIdx.x;
    if (i < N) dinv[i] = 1.0f / sqrtf((float)(deg[i] + 1));
}

// ---------------- per-graph exclusive scan of deg -> CSR offsets + cursor copy ----------------
__global__ void scan_k(const int* __restrict__ deg, int* __restrict__ off,
                       int* __restrict__ cursor) {
    int g = blockIdx.x, t = threadIdx.x;          // 256 threads
    const int* dg = deg + (size_t)g * NPG;
    int base = t * 4;
    int v0 = 0, v1 = 0, v2 = 0, v3 = 0;
    if (base + 0 < NPG) v0 = dg[base + 0];
    if (base + 1 < NPG) v1 = dg[base + 1];
    if (base + 2 < NPG) v2 = dg[base + 2];
    if (base + 3 < NPG) v3 = dg[base + 3];
    int s = v0 + v1 + v2 + v3;
    __shared__ int red[256];
    red[t] = s;
    __syncthreads();
    for (int o = 1; o < 256; o <<= 1) {
        int x = (t >= o) ? red[t - o] : 0;
        __syncthreads();
        red[t] += x;
        __syncthreads();
    }
    int excl = red[t] - s;
    int gb = g * EPG;
    int p = gb + excl;
    if (base + 0 < NPG) { off[(size_t)g * NPG + base + 0] = p; cursor[(size_t)g * NPG + base + 0] = p; p += v0; }
    if (base + 1 < NPG) { off[(size_t)g * NPG + base + 1] = p; cursor[(size_t)g * NPG + base + 1] = p; p += v1; }
    if (base + 2 < NPG) { off[(size_t)g * NPG + base + 2] = p; cursor[(size_t)g * NPG + base + 2] = p; p += v2; }
    if (base + 3 < NPG) { off[(size_t)g * NPG + base + 3] = p; cursor[(size_t)g * NPG + base + 3] = p; p += v3; }
}

// ---------------- CSR fill: csr[pos] = src for edges grouped by dst ----------------
__global__ void csr_fill_k(const int* __restrict__ ei, int* __restrict__ cursor,
                           int* __restrict__ csr, int E) {
    int e = blockIdx.x * 256 + threadIdx.x;
    if (e < E) {
        int s = ei[e], d = ei[E + e];
        int p = atomicAdd(&cursor[d], 1);
        csr[p] = s;
    }
}

// ---------------- h = x @ W : register-tiled, 2 rows/thread, W in LDS ----------------
__global__ __launch_bounds__(256) void gemm_k(const float* __restrict__ x,
                                              const float* __restrict__ W,
                                              float* __restrict__ h, int N) {
    __shared__ float sW[C * C];
    int t = threadIdx.x;
    for (int i = t; i < C * C / 4; i += 256) ((float4*)sW)[i] = ((const float4*)W)[i];
    __syncthreads();
    int r0 = blockIdx.x * 512 + t;
    int r1 = r0 + 256;
    if (r0 >= N) return;
    bool has1 = (r1 < N);
    const float4* x0 = (const float4*)(x + (size_t)r0 * C);
    const float4* x1 = (const float4*)(x + (size_t)(has1 ? r1 : r0) * C);
    float acc0[C], acc1[C];
#pragma unroll
    for (int i = 0; i < C; ++i) { acc0[i] = 0.f; acc1[i] = 0.f; }
    float4 a0 = x0[0], a1 = x1[0];
    for (int k4 = 0; k4 < 16; ++k4) {
        float4 b0, b1;
        if (k4 < 15) { b0 = x0[k4 + 1]; b1 = x1[k4 + 1]; }
        const float4* wr = (const float4*)(sW + k4 * 4 * C);
        const float* a0f = (const float*)&a0;
        const float* a1f = (const float*)&a1;
#pragma unroll
        for (int c4 = 0; c4 < 16; ++c4) {
            float4 w[4];
            w[0] = wr[c4]; w[1] = wr[16 + c4]; w[2] = wr[32 + c4]; w[3] = wr[48 + c4];
            const float* wf = (const float*)w;
#pragma unroll
            for (int j = 0; j < 4; ++j) {
                float s0 = acc0[c4 * 4 + j], s1 = acc1[c4 * 4 + j];
#pragma unroll
                for (int kk = 0; kk < 4; ++kk) {
                    float wv = wf[kk * 4 + j];
                    s0 = fmaf(a0f[kk], wv, s0);
                    s1 = fmaf(a1f[kk], wv, s1);
                }
                acc0[c4 * 4 + j] = s0; acc1[c4 * 4 + j] = s1;
            }
        }
        a0 = b0; a1 = b1;
    }
    float4* h0 = (float4*)(h + (size_t)r0 * C);
#pragma unroll
    for (int q = 0; q < 16; ++q) h0[q] = ((float4*)acc0)[q];
    if (has1) {
        float4* h1 = (float4*)(h + (size_t)r1 * C);
#pragma unroll
        for (int q = 0; q < 16; ++q) h1[q] = ((float4*)acc1)[q];
    }
}

// ---------------- gather aggregation: one wave per node, lane = channel ----------------
// XCD-swizzled: all blocks of a graph land on the same XCD so its h slice (256KB)
// stays in that XCD's 4MB L2. Lane-parallel index staging + shfl broadcast.
__global__ __launch_bounds__(256) void gather_k(const int* __restrict__ csr,
                                                const int* __restrict__ off,
                                                const int* __restrict__ deg,
                                                const float* __restrict__ h,
                                                const float* __restrict__ dinv,
                                                const float* __restrict__ bias,
                                                float* __restrict__ out2, int N, int B) {
    int b = blockIdx.x;
    int wave = threadIdx.x >> 6;
    int lane = threadIdx.x & 63;
    int node;
    if ((B & 7) == 0) {
        int xcd = b & 7, slot = b >> 3;           // runtime maps block i -> XCD i%8
        int gpx = B >> 3;                          // graphs per XCD
        int g = xcd * gpx + slot / (NPG / 4);
        int blkin = slot % (NPG / 4);
        node = g * NPG + blkin * 4 + wave;
    } else {
        node = b * 4 + wave;
    }
    if (node >= N) return;
    int o0 = off[node], dg = deg[node];
    int sv = 0; float wv = 0.f;
    if (lane < dg) { sv = csr[o0 + lane]; wv = dinv[sv]; }
    float acc = 0.f;
    int jmax = dg < 64 ? dg : 64;
    int j = 0;
    for (; j + 4 <= jmax; j += 4) {
        int   s0 = __shfl(sv, j + 0); float w0 = __shfl(wv, j + 0);
        int   s1 = __shfl(sv, j + 1); float w1 = __shfl(wv, j + 1);
        int   s2 = __shfl(sv, j + 2); float w2 = __shfl(wv, j + 2);
        int   s3 = __shfl(sv, j + 3); float w3 = __shfl(wv, j + 3);
        float h0 = h[(size_t)s0 * C + lane];
        float h1 = h[(size_t)s1 * C + lane];
        float h2 = h[(size_t)s2 * C + lane];
        float h3 = h[(size_t)s3 * C + lane];
        acc = fmaf(h0, w0, acc);
        acc = fmaf(h1, w1, acc);
        acc = fmaf(h2, w2, acc);
        acc = fmaf(h3, w3, acc);
    }
    for (; j < jmax; ++j) {
        int s = __shfl(sv, j); float w = __shfl(wv, j);
        acc = fmaf(h[(size_t)s * C + lane], w, acc);
    }
    for (; j < dg; ++j) {                          // ultra-rare deg>64 tail
        int s = csr[o0 + j];
        acc = fmaf(h[(size_t)s * C + lane], dinv[s], acc);
    }
    float di = dinv[node];
    float hv = h[(size_t)node * C + lane];
    out2[(size_t)node * C + lane] = bias[lane] + di * acc + di * di * hv;
}

// ---------------- per-graph centroid: partial sums (4 blocks/graph) + finalize ----------------
__global__ void centroid_part_k(const float* __restrict__ out2, float* __restrict__ pcen) {
    int blk = blockIdx.x;            // g*4 + p
    int g = blk >> 2, p = blk & 3;
    int t = threadIdx.x;             // 256
    int c = t & 63, q = t >> 6;
    const float* base = out2 + (size_t)g * NPG * C;
    int n0 = p * 250, n1 = n0 + 250;
    float acc = 0.f;
    for (int n = n0 + q; n < n1; n += 4) acc += base[(size_t)n * C + c];
    __shared__ float red[256];
    red[t] = acc;
    __syncthreads();
    if (t < 64) pcen[(size_t)blk * C + t] = red[t] + red[64 + t] + red[128 + t] + red[192 + t];
}

__global__ void cen_fin_k(const float* __restrict__ pcen, float* __restrict__ cen,
                          float* __restrict__ cnorm) {
    int g = blockIdx.x, c = threadIdx.x;   // 64 threads
    float s = pcen[(size_t)(g * 4 + 0) * C + c] + pcen[(size_t)(g * 4 + 1) * C + c]
            + pcen[(size_t)(g * 4 + 2) * C + c] + pcen[(size_t)(g * 4 + 3) * C + c];
    float m = s / 1000.0f;
    cen[g * C + c] = m;
    float v = m * m;
    for (int o = 32; o > 0; o >>= 1) v += __shfl_down(v, o, 64);
    if (c == 0) cnorm[g] = sqrtf(v);
}

// cosine similarity of each node row vs its graph centroid
__global__ void score_k(const float* __restrict__ out2, const float* __restrict__ cen,
                        const float* __restrict__ cnorm, float* __restrict__ score, int N) {
    int i = blockIdx.x * 256 + threadIdx.x;
    if (i < N) {
        int g = i / NPG;
        const float4* xr = (const float4*)(out2 + (size_t)i * C);
        const float4* cr = (const float4*)(cen + g * C);
        float num = 0.f, sq = 0.f;
#pragma unroll
        for (int q = 0; q < 16; ++q) {
            float4 a = xr[q], b = cr[q];
            num += a.x * b.x + a.y * b.y + a.z * b.z + a.w * b.w;
            sq  += a.x * a.x + a.y * a.y + a.z * a.z + a.w * a.w;
        }
        float den = sqrtf(sq) * cnorm[g] + 1e-8f;
        score[i] = num / den;
    }
}

// per-graph KL(softmax || uniform)
__global__ void softmax_kl_k(const float* __restrict__ score, float* __restrict__ o_kl) {
    int g = blockIdx.x, t = threadIdx.x;          // 256 threads
    const float* s = score + (size_t)g * NPG;
    __shared__ float red[256];
    float mx = -INFINITY;
    for (int i = t; i < NPG; i += 256) mx = fmaxf(mx, s[i]);
    red[t] = mx;
    __syncthreads();
    for (int w = 128; w > 0; w >>= 1) { if (t < w) red[t] = fmaxf(red[t], red[t + w]); __syncthreads(); }
    mx = red[0];
    __syncthreads();
    float se = 0.f;
    for (int i = t; i < NPG; i += 256) se += expf(s[i] - mx);
    red[t] = se;
    __syncthreads();
    for (int w = 128; w > 0; w >>= 1) { if (t < w) red[t] += red[t + w]; __syncthreads(); }
    float lse = logf(red[0]);
    __syncthreads();
    float kl = 0.f;
    const float ln_npg = 6.9077552790f;           // log(1000) in f32
    for (int i = t; i < NPG; i += 256) {
        float lp = s[i] - mx - lse;
        kl += expf(lp) * (lp + ln_npg);
    }
    red[t] = kl;
    __syncthreads();
    for (int w = 128; w > 0; w >>= 1) { if (t < w) red[t] += red[t + w]; __syncthreads(); }
    if (t == 0) o_kl[g] = red[0];
}

// ---------------- per-graph full descending stable argsort (bitonic, 1024) ----------------
__global__ void sort_k(const float* __restrict__ score, int* __restrict__ sidx,
                       float* __restrict__ o_ind) {
    __shared__ unsigned long long kk[1024];
    int g = blockIdx.x, t = threadIdx.x;          // 512 threads
    for (int i = t; i < 1024; i += 512) {
        unsigned long long v;
        if (i < NPG) {
            unsigned u = __float_as_uint(score[(size_t)g * NPG + i]);
            u = (u & 0x80000000u) ? ~u : (u | 0x80000000u);     // ascending order map
            v = ((unsigned long long)(~u) << 32) | (unsigned)i; // descending score, asc idx
        } else {
            v = ~0ULL;
        }
        kk[i] = v;
    }
    __syncthreads();
    for (int k = 2; k <= 1024; k <<= 1) {
        for (int j = k >> 1; j > 0; j >>= 1) {
            for (int i = t; i < 1024; i += 512) {
                int ixj = i ^ j;
                if (ixj > i) {
                    unsigned long long a = kk[i], b = kk[ixj];
                    bool up = ((i & k) == 0);
                    if ((a > b) == up) { kk[i] = b; kk[ixj] = a; }
                }
            }
            __syncthreads();
        }
    }
    for (int i = t; i < NPG; i += 512) {
        int idx = (int)(kk[i] & 0xFFFFFFFFULL);
        sidx[(size_t)g * NPG + i] = idx;
        o_ind[(size_t)g * NPG + i] = (float)idx;
    }
}

// ---------------- top-K gather: x_new, perm, batch_new, mapping ----------------
__global__ void topk_k(const int* __restrict__ sidx, const float* __restrict__ score,
                       const float* __restrict__ out2, int* __restrict__ mapping,
                       float* __restrict__ o_xnew, float* __restrict__ o_batch,
                       float* __restrict__ o_perm, int BK) {
    int j = blockIdx.x * 256 + threadIdx.x;
    if (j < BK) {
        int b = j / KTOP, r = j - b * KTOP;
        int node = sidx[(size_t)b * NPG + r];
        int gn = b * NPG + node;
        mapping[gn] = j;
        o_perm[j] = (float)gn;
        o_batch[j] = (float)b;
        float tn = tanhf(score[gn]);
        const float4* src = (const float4*)(out2 + (size_t)gn * C);
        float4* dst = (float4*)(o_xnew + (size_t)j * C);
#pragma unroll
        for (int q = 0; q < 16; ++q) {
            float4 v = src[q];
            v.x *= tn; v.y *= tn; v.z *= tn; v.w *= tn;
            dst[q] = v;
        }
    }
}

// ---------------- edge re-index + mask + attr ----------------
__global__ void edge_out_k(const int* __restrict__ ei, const float* __restrict__ eattr,
                           const int* __restrict__ mapping, float* __restrict__ o_newei,
                           float* __restrict__ o_eattr, float* __restrict__ o_mask, int E) {
    int e = blockIdx.x * 256 + threadIdx.x;
    if (e < E) {
        int m0 = mapping[ei[e]];
        int m1 = mapping[ei[E + e]];
        o_newei[e] = (float)m0;
        o_newei[E + e] = (float)m1;
        bool mk = (m0 >= 0) && (m1 >= 0);
        o_mask[e] = mk ? 1.0f : 0.0f;
        o_eattr[e] = mk ? eattr[e] : 0.0f;
    }
}

extern "C" void kernel_launch(void* const* d_in, const int* in_sizes, int n_in,
                              void* d_out, int out_size, void* d_ws, size_t ws_size,
                              hipStream_t stream) {
    (void)n_in; (void)out_size; (void)ws_size;
    const float* x     = (const float*)d_in[1];
    const int*   ei    = (const int*)d_in[2];
    const float* eattr = (const float*)d_in[3];
    const float* W     = (const float*)d_in[5];
    const float* bias  = (const float*)d_in[6];

    const int N  = in_sizes[1] / C;    // 256000
    const int E  = in_sizes[2] / 2;    // 4096000
    const int B  = N / NPG;            // 256
    const int BK = B * KTOP;           // 128000

    // workspace layout
    char* wsp = (char*)d_ws;
    float* out2    = (float*)wsp; wsp += (size_t)N * C * 4;   // 65.5 MB
    float* dinv    = (float*)wsp; wsp += (size_t)N * 4;
    float* score   = (float*)wsp; wsp += (size_t)N * 4;
    float* cen     = (float*)wsp; wsp += (size_t)B * C * 4;
    float* cnorm   = (float*)wsp; wsp += 1024;                // B*4
    int*   sidx    = (int*)wsp;   wsp += (size_t)B * NPG * 4;
    int*   mapping = (int*)wsp;   wsp += (size_t)N * 4;
    int*   deg     = (int*)wsp;   wsp += (size_t)N * 4;
    int*   off     = (int*)wsp;   wsp += (size_t)N * 4;
    int*   cursor  = (int*)wsp;   wsp += (size_t)N * 4;
    float* pcen    = (float*)wsp; wsp += (size_t)B * 4 * C * 4;

    // output layout (flat f32, reference return order)
    float* out     = (float*)d_out;
    float* o_xnew  = out;                                   // BK*C
    float* o_newei = o_xnew + (size_t)BK * C;               // 2E
    float* o_eattr = o_newei + 2 * (size_t)E;               // E
    float* o_mask  = o_eattr + (size_t)E;                   // E
    float* o_batch = o_mask + (size_t)E;                    // BK
    float* o_perm  = o_batch + (size_t)BK;                  // BK
    float* o_kl    = o_perm + (size_t)BK;                   // B
    float* o_ind   = o_kl + (size_t)B;                      // B*NPG

    // scratch aliased onto d_out (dead before those outputs are written)
    float* hbuf = out;                 // N*C floats
    int*   csr  = (int*)o_eattr;       // E ints

    hipMemsetAsync(deg, 0, (size_t)N * 4, stream);
    hipMemsetAsync(mapping, 0xFF, (size_t)N * 4, stream);   // -1

    deg_count_k<<<(E + 255) / 256, 256, 0, stream>>>(ei, deg, E);
    dinv_k<<<(N + 255) / 256, 256, 0, stream>>>(deg, dinv, N);
    scan_k<<<B, 256, 0, stream>>>(deg, off, cursor);
    csr_fill_k<<<(E + 255) / 256, 256, 0, stream>>>(ei, cursor, csr, E);
    gemm_k<<<(N + 511) / 512, 256, 0, stream>>>(x, W, hbuf, N);
    gather_k<<<(N + 3) / 4, 256, 0, stream>>>(csr, off, deg, hbuf, dinv, bias, out2, N, B);
    centroid_part_k<<<B * 4, 256, 0, stream>>>(out2, pcen);
    cen_fin_k<<<B, 64, 0, stream>>>(pcen, cen, cnorm);
    score_k<<<(N + 255) / 256, 256, 0, stream>>>(out2, cen, cnorm, score, N);
    softmax_kl_k<<<B, 256, 0, stream>>>(score, o_kl);
    sort_k<<<B, 512, 0, stream>>>(score, sidx, o_ind);
    topk_k<<<(BK + 255) / 256, 256, 0, stream>>>(sidx, score, out2, mapping,
                                                 o_xnew, o_batch, o_perm, BK);
    edge_out_k<<<(E + 255) / 256, 256, 0, stream>>>(ei, eattr, mapping,
                                                    o_newei, o_eattr, o_mask, E);
}

// Round 5
// 506.828 us; speedup vs baseline: 7.9609x; 1.3379x over previous
//
#include <hip/hip_runtime.h>
#include <math.h>

#define NPG 1000
#define KTOP 500
#define C 64
#define EPG 16000   // edges per graph = NPG * DEG

// ---------------- fused per-graph CSR build: count + scan + scatter in LDS ----------------
// One block per graph. Edge list is graph-major: edges [g*EPG,(g+1)*EPG) belong to
// graph g and node ids lie in [g*NPG,(g+1)*NPG). All scatter traffic stays in LDS;
// global csr is written fully coalesced.
__global__ __launch_bounds__(256) void build_graph_k(const int* __restrict__ ei, int E,
                                                     int* __restrict__ deg,
                                                     float* __restrict__ dinv,
                                                     int* __restrict__ off,
                                                     int* __restrict__ csr) {
    int g = blockIdx.x, t = threadIdx.x;
    __shared__ int cnt[NPG];               // counts, then cursors
    __shared__ int soff[NPG];              // local start offsets
    __shared__ unsigned short lcsr[EPG];   // src local ids, dst-grouped
    __shared__ int red[256];
    const int gbase = g * NPG;
    const int ebase = g * EPG;
    const int* __restrict__ srcp = ei + ebase;
    const int* __restrict__ dstp = ei + E + ebase;

    for (int i = t; i < NPG; i += 256) cnt[i] = 0;
    __syncthreads();
    // phase 1: count in-degree (LDS atomics)
    for (int i = t; i < EPG; i += 256) atomicAdd(&cnt[dstp[i] - gbase], 1);
    __syncthreads();
    // phase 2: exclusive scan over 1000 counts (4 per thread + Hillis-Steele on 256)
    int base = t * 4;
    int v0 = 0, v1 = 0, v2 = 0, v3 = 0;
    if (base + 0 < NPG) v0 = cnt[base + 0];
    if (base + 1 < NPG) v1 = cnt[base + 1];
    if (base + 2 < NPG) v2 = cnt[base + 2];
    if (base + 3 < NPG) v3 = cnt[base + 3];
    int s = v0 + v1 + v2 + v3;
    red[t] = s;
    __syncthreads();
    for (int o = 1; o < 256; o <<= 1) {
        int xx = (t >= o) ? red[t - o] : 0;
        __syncthreads();
        red[t] += xx;
        __syncthreads();
    }
    int p = red[t] - s;                    // exclusive prefix
    if (base + 0 < NPG) { soff[base + 0] = p; p += v0; }
    if (base + 1 < NPG) { soff[base + 1] = p; p += v1; }
    if (base + 2 < NPG) { soff[base + 2] = p; p += v2; }
    if (base + 3 < NPG) { soff[base + 3] = p; p += v3; }
    __syncthreads();
    // outputs: deg, dinv, off (coalesced)
    for (int i = t; i < NPG; i += 256) {
        int d = cnt[i];
        deg[gbase + i] = d;
        dinv[gbase + i] = 1.0f / sqrtf((float)(d + 1));
        off[gbase + i] = ebase + soff[i];
    }
    __syncthreads();
    // reset cursors
    for (int i = t; i < NPG; i += 256) cnt[i] = soff[i];
    __syncthreads();
    // phase 3: scatter src into dst-grouped order (LDS cursor atomics + LDS writes)
    for (int i = t; i < EPG; i += 256) {
        int d = dstp[i] - gbase;
        int pos = atomicAdd(&cnt[d], 1);
        lcsr[pos] = (unsigned short)(srcp[i] - gbase);
    }
    __syncthreads();
    // phase 4: dump csr as coalesced int4 stores (EPG % 4 == 0)
    int4* co = (int4*)(csr + ebase);
    for (int i = t; i < EPG / 4; i += 256) {
        int4 v;
        v.x = gbase + (int)lcsr[i * 4 + 0];
        v.y = gbase + (int)lcsr[i * 4 + 1];
        v.z = gbase + (int)lcsr[i * 4 + 2];
        v.w = gbase + (int)lcsr[i * 4 + 3];
        co[i] = v;
    }
}

// ---------------- h = x @ W : register-tiled, 2 rows/thread, W in LDS ----------------
__global__ __launch_bounds__(256) void gemm_k(const float* __restrict__ x,
                                              const float* __restrict__ W,
                                              float* __restrict__ h, int N) {
    __shared__ float sW[C * C];
    int t = threadIdx.x;
    for (int i = t; i < C * C / 4; i += 256) ((float4*)sW)[i] = ((const float4*)W)[i];
    __syncthreads();
    int r0 = blockIdx.x * 512 + t;
    int r1 = r0 + 256;
    if (r0 >= N) return;
    bool has1 = (r1 < N);
    const float4* x0 = (const float4*)(x + (size_t)r0 * C);
    const float4* x1 = (const float4*)(x + (size_t)(has1 ? r1 : r0) * C);
    float acc0[C], acc1[C];
#pragma unroll
    for (int i = 0; i < C; ++i) { acc0[i] = 0.f; acc1[i] = 0.f; }
    float4 a0 = x0[0], a1 = x1[0];
    for (int k4 = 0; k4 < 16; ++k4) {
        float4 b0, b1;
        if (k4 < 15) { b0 = x0[k4 + 1]; b1 = x1[k4 + 1]; }
        const float4* wr = (const float4*)(sW + k4 * 4 * C);
        const float* a0f = (const float*)&a0;
        const float* a1f = (const float*)&a1;
#pragma unroll
        for (int c4 = 0; c4 < 16; ++c4) {
            float4 w[4];
            w[0] = wr[c4]; w[1] = wr[16 + c4]; w[2] = wr[32 + c4]; w[3] = wr[48 + c4];
            const float* wf = (const float*)w;
#pragma unroll
            for (int j = 0; j < 4; ++j) {
                float s0 = acc0[c4 * 4 + j], s1 = acc1[c4 * 4 + j];
#pragma unroll
                for (int kk = 0; kk < 4; ++kk) {
                    float wv = wf[kk * 4 + j];
                    s0 = fmaf(a0f[kk], wv, s0);
                    s1 = fmaf(a1f[kk], wv, s1);
                }
                acc0[c4 * 4 + j] = s0; acc1[c4 * 4 + j] = s1;
            }
        }
        a0 = b0; a1 = b1;
    }
    float4* h0 = (float4*)(h + (size_t)r0 * C);
#pragma unroll
    for (int q = 0; q < 16; ++q) h0[q] = ((float4*)acc0)[q];
    if (has1) {
        float4* h1 = (float4*)(h + (size_t)r1 * C);
#pragma unroll
        for (int q = 0; q < 16; ++q) h1[q] = ((float4*)acc1)[q];
    }
}

// ---------------- gather aggregation: one wave per node, lane = channel ----------------
// XCD-swizzled so each graph's h slice stays in one XCD's L2.
__global__ __launch_bounds__(256) void gather_k(const int* __restrict__ csr,
                                                const int* __restrict__ off,
                                                const int* __restrict__ deg,
                                                const float* __restrict__ h,
                                                const float* __restrict__ dinv,
                                                const float* __restrict__ bias,
                                                float* __restrict__ out2, int N, int B) {
    int b = blockIdx.x;
    int wave = threadIdx.x >> 6;
    int lane = threadIdx.x & 63;
    int node;
    if ((B & 7) == 0) {
        int xcd = b & 7, slot = b >> 3;
        int gpx = B >> 3;
        int g = xcd * gpx + slot / (NPG / 4);
        int blkin = slot % (NPG / 4);
        node = g * NPG + blkin * 4 + wave;
    } else {
        node = b * 4 + wave;
    }
    if (node >= N) return;
    int o0 = off[node], dg = deg[node];
    int sv = 0; float wv = 0.f;
    if (lane < dg) { sv = csr[o0 + lane]; wv = dinv[sv]; }
    float acc = 0.f;
    int jmax = dg < 64 ? dg : 64;
    int j = 0;
    for (; j + 4 <= jmax; j += 4) {
        int   s0 = __shfl(sv, j + 0); float w0 = __shfl(wv, j + 0);
        int   s1 = __shfl(sv, j + 1); float w1 = __shfl(wv, j + 1);
        int   s2 = __shfl(sv, j + 2); float w2 = __shfl(wv, j + 2);
        int   s3 = __shfl(sv, j + 3); float w3 = __shfl(wv, j + 3);
        float h0 = h[(size_t)s0 * C + lane];
        float h1 = h[(size_t)s1 * C + lane];
        float h2 = h[(size_t)s2 * C + lane];
        float h3 = h[(size_t)s3 * C + lane];
        acc = fmaf(h0, w0, acc);
        acc = fmaf(h1, w1, acc);
        acc = fmaf(h2, w2, acc);
        acc = fmaf(h3, w3, acc);
    }
    for (; j < jmax; ++j) {
        int s = __shfl(sv, j); float w = __shfl(wv, j);
        acc = fmaf(h[(size_t)s * C + lane], w, acc);
    }
    for (; j < dg; ++j) {
        int s = csr[o0 + j];
        acc = fmaf(h[(size_t)s * C + lane], dinv[s], acc);
    }
    float di = dinv[node];
    float hv = h[(size_t)node * C + lane];
    out2[(size_t)node * C + lane] = bias[lane] + di * acc + di * di * hv;
}

// ---------------- per-graph centroid: partial sums (4 blocks/graph) + finalize ----------------
__global__ void centroid_part_k(const float* __restrict__ out2, float* __restrict__ pcen) {
    int blk = blockIdx.x;
    int g = blk >> 2, p = blk & 3;
    int t = threadIdx.x;
    int c = t & 63, q = t >> 6;
    const float* base = out2 + (size_t)g * NPG * C;
    int n0 = p * 250, n1 = n0 + 250;
    float acc = 0.f;
    for (int n = n0 + q; n < n1; n += 4) acc += base[(size_t)n * C + c];
    __shared__ float red[256];
    red[t] = acc;
    __syncthreads();
    if (t < 64) pcen[(size_t)blk * C + t] = red[t] + red[64 + t] + red[128 + t] + red[192 + t];
}

__global__ void cen_fin_k(const float* __restrict__ pcen, float* __restrict__ cen,
                          float* __restrict__ cnorm) {
    int g = blockIdx.x, c = threadIdx.x;   // 64 threads
    float s = pcen[(size_t)(g * 4 + 0) * C + c] + pcen[(size_t)(g * 4 + 1) * C + c]
            + pcen[(size_t)(g * 4 + 2) * C + c] + pcen[(size_t)(g * 4 + 3) * C + c];
    float m = s / 1000.0f;
    cen[g * C + c] = m;
    float v = m * m;
    for (int o = 32; o > 0; o >>= 1) v += __shfl_down(v, o, 64);
    if (c == 0) cnorm[g] = sqrtf(v);
}

// cosine similarity of each node row vs its graph centroid
__global__ void score_k(const float* __restrict__ out2, const float* __restrict__ cen,
                        const float* __restrict__ cnorm, float* __restrict__ score, int N) {
    int i = blockIdx.x * 256 + threadIdx.x;
    if (i < N) {
        int g = i / NPG;
        const float4* xr = (const float4*)(out2 + (size_t)i * C);
        const float4* cr = (const float4*)(cen + g * C);
        float num = 0.f, sq = 0.f;
#pragma unroll
        for (int q = 0; q < 16; ++q) {
            float4 a = xr[q], b = cr[q];
            num += a.x * b.x + a.y * b.y + a.z * b.z + a.w * b.w;
            sq  += a.x * a.x + a.y * a.y + a.z * a.z + a.w * a.w;
        }
        float den = sqrtf(sq) * cnorm[g] + 1e-8f;
        score[i] = num / den;
    }
}

// per-graph KL(softmax || uniform)
__global__ void softmax_kl_k(const float* __restrict__ score, float* __restrict__ o_kl) {
    int g = blockIdx.x, t = threadIdx.x;
    const float* s = score + (size_t)g * NPG;
    __shared__ float red[256];
    float mx = -INFINITY;
    for (int i = t; i < NPG; i += 256) mx = fmaxf(mx, s[i]);
    red[t] = mx;
    __syncthreads();
    for (int w = 128; w > 0; w >>= 1) { if (t < w) red[t] = fmaxf(red[t], red[t + w]); __syncthreads(); }
    mx = red[0];
    __syncthreads();
    float se = 0.f;
    for (int i = t; i < NPG; i += 256) se += expf(s[i] - mx);
    red[t] = se;
    __syncthreads();
    for (int w = 128; w > 0; w >>= 1) { if (t < w) red[t] += red[t + w]; __syncthreads(); }
    float lse = logf(red[0]);
    __syncthreads();
    float kl = 0.f;
    const float ln_npg = 6.9077552790f;
    for (int i = t; i < NPG; i += 256) {
        float lp = s[i] - mx - lse;
        kl += expf(lp) * (lp + ln_npg);
    }
    red[t] = kl;
    __syncthreads();
    for (int w = 128; w > 0; w >>= 1) { if (t < w) red[t] += red[t + w]; __syncthreads(); }
    if (t == 0) o_kl[g] = red[0];
}

// ---------------- per-graph full descending stable argsort (bitonic, 1024) ----------------
__global__ void sort_k(const float* __restrict__ score, int* __restrict__ sidx,
                       float* __restrict__ o_ind) {
    __shared__ unsigned long long kk[1024];
    int g = blockIdx.x, t = threadIdx.x;          // 512 threads
    for (int i = t; i < 1024; i += 512) {
        unsigned long long v;
        if (i < NPG) {
            unsigned u = __float_as_uint(score[(size_t)g * NPG + i]);
            u = (u & 0x80000000u) ? ~u : (u | 0x80000000u);
            v = ((unsigned long long)(~u) << 32) | (unsigned)i;
        } else {
            v = ~0ULL;
        }
        kk[i] = v;
    }
    __syncthreads();
    for (int k = 2; k <= 1024; k <<= 1) {
        for (int j = k >> 1; j > 0; j >>= 1) {
            for (int i = t; i < 1024; i += 512) {
                int ixj = i ^ j;
                if (ixj > i) {
                    unsigned long long a = kk[i], b = kk[ixj];
                    bool up = ((i & k) == 0);
                    if ((a > b) == up) { kk[i] = b; kk[ixj] = a; }
                }
            }
            __syncthreads();
        }
    }
    for (int i = t; i < NPG; i += 512) {
        int idx = (int)(kk[i] & 0xFFFFFFFFULL);
        sidx[(size_t)g * NPG + i] = idx;
        o_ind[(size_t)g * NPG + i] = (float)idx;
    }
}

// ---------------- top-K gather: x_new, perm, batch_new, mapping ----------------
__global__ void topk_k(const int* __restrict__ sidx, const float* __restrict__ score,
                       const float* __restrict__ out2, int* __restrict__ mapping,
                       float* __restrict__ o_xnew, float* __restrict__ o_batch,
                       float* __restrict__ o_perm, int BK) {
    int j = blockIdx.x * 256 + threadIdx.x;
    if (j < BK) {
        int b = j / KTOP, r = j - b * KTOP;
        int node = sidx[(size_t)b * NPG + r];
        int gn = b * NPG + node;
        mapping[gn] = j;
        o_perm[j] = (float)gn;
        o_batch[j] = (float)b;
        float tn = tanhf(score[gn]);
        const float4* src = (const float4*)(out2 + (size_t)gn * C);
        float4* dst = (float4*)(o_xnew + (size_t)j * C);
#pragma unroll
        for (int q = 0; q < 16; ++q) {
            float4 v = src[q];
            v.x *= tn; v.y *= tn; v.z *= tn; v.w *= tn;
            dst[q] = v;
        }
    }
}

// ---------------- edge re-index + mask + attr ----------------
__global__ void edge_out_k(const int* __restrict__ ei, const float* __restrict__ eattr,
                           const int* __restrict__ mapping, float* __restrict__ o_newei,
                           float* __restrict__ o_eattr, float* __restrict__ o_mask, int E) {
    int e = blockIdx.x * 256 + threadIdx.x;
    if (e < E) {
        int m0 = mapping[ei[e]];
        int m1 = mapping[ei[E + e]];
        o_newei[e] = (float)m0;
        o_newei[E + e] = (float)m1;
        bool mk = (m0 >= 0) && (m1 >= 0);
        o_mask[e] = mk ? 1.0f : 0.0f;
        o_eattr[e] = mk ? eattr[e] : 0.0f;
    }
}

extern "C" void kernel_launch(void* const* d_in, const int* in_sizes, int n_in,
                              void* d_out, int out_size, void* d_ws, size_t ws_size,
                              hipStream_t stream) {
    (void)n_in; (void)out_size; (void)ws_size;
    const float* x     = (const float*)d_in[1];
    const int*   ei    = (const int*)d_in[2];
    const float* eattr = (const float*)d_in[3];
    const float* W     = (const float*)d_in[5];
    const float* bias  = (const float*)d_in[6];

    const int N  = in_sizes[1] / C;    // 256000
    const int E  = in_sizes[2] / 2;    // 4096000
    const int B  = N / NPG;            // 256
    const int BK = B * KTOP;           // 128000

    // workspace layout
    char* wsp = (char*)d_ws;
    float* out2    = (float*)wsp; wsp += (size_t)N * C * 4;   // 65.5 MB
    float* dinv    = (float*)wsp; wsp += (size_t)N * 4;
    float* score   = (float*)wsp; wsp += (size_t)N * 4;
    float* cen     = (float*)wsp; wsp += (size_t)B * C * 4;
    float* cnorm   = (float*)wsp; wsp += 1024;
    int*   sidx    = (int*)wsp;   wsp += (size_t)B * NPG * 4;
    int*   mapping = (int*)wsp;   wsp += (size_t)N * 4;
    int*   deg     = (int*)wsp;   wsp += (size_t)N * 4;
    int*   off     = (int*)wsp;   wsp += (size_t)N * 4;
    float* pcen    = (float*)wsp; wsp += (size_t)B * 4 * C * 4;

    // output layout (flat f32, reference return order)
    float* out     = (float*)d_out;
    float* o_xnew  = out;                                   // BK*C
    float* o_newei = o_xnew + (size_t)BK * C;               // 2E
    float* o_eattr = o_newei + 2 * (size_t)E;               // E
    float* o_mask  = o_eattr + (size_t)E;                   // E
    float* o_batch = o_mask + (size_t)E;                    // BK
    float* o_perm  = o_batch + (size_t)BK;                  // BK
    float* o_kl    = o_perm + (size_t)BK;                   // B
    float* o_ind   = o_kl + (size_t)B;                      // B*NPG

    // scratch aliased onto d_out (dead before those outputs are written)
    float* hbuf = out;                 // N*C floats
    int*   csr  = (int*)o_eattr;       // E ints

    hipMemsetAsync(mapping, 0xFF, (size_t)N * 4, stream);   // -1

    build_graph_k<<<B, 256, 0, stream>>>(ei, E, deg, dinv, off, csr);
    gemm_k<<<(N + 511) / 512, 256, 0, stream>>>(x, W, hbuf, N);
    gather_k<<<(N + 3) / 4, 256, 0, stream>>>(csr, off, deg, hbuf, dinv, bias, out2, N, B);
    centroid_part_k<<<B * 4, 256, 0, stream>>>(out2, pcen);
    cen_fin_k<<<B, 64, 0, stream>>>(pcen, cen, cnorm);
    score_k<<<(N + 255) / 256, 256, 0, stream>>>(out2, cen, cnorm, score, N);
    softmax_kl_k<<<B, 256, 0, stream>>>(score, o_kl);
    sort_k<<<B, 512, 0, stream>>>(score, sidx, o_ind);
    topk_k<<<(BK + 255) / 256, 256, 0, stream>>>(sidx, score, out2, mapping,
                                                 o_xnew, o_batch, o_perm, BK);
    edge_out_k<<<(E + 255) / 256, 256, 0, stream>>>(ei, eattr, mapping,
                                                    o_newei, o_eattr, o_mask, E);
}